// Round 4
// baseline (234.828 us; speedup 1.0000x reference)
//
#include <hip/hip_runtime.h>
#include <hip/hip_bf16.h>
#include <stdint.h>

typedef __attribute__((ext_vector_type(8))) __bf16 bf16x8;
typedef __attribute__((ext_vector_type(4))) float f32x4;
typedef __attribute__((ext_vector_type(16))) float f32x16;
typedef __attribute__((ext_vector_type(8))) uint16_t u16x8;

__device__ inline uint16_t f2bf(float x) {
  union { float f; uint32_t u; } v; v.f = x;
  uint32_t r = v.u + 0x7fffu + ((v.u >> 16) & 1u);
  return (uint16_t)(r >> 16);
}

#define MFMA16(a, b, c) __builtin_amdgcn_mfma_f32_16x16x32_bf16(a, b, c, 0, 0, 0)
#define MFMA32(a, b, c) __builtin_amdgcn_mfma_f32_32x32x16_bf16(a, b, c, 0, 0, 0)
#define GLOAD16(g, l) __builtin_amdgcn_global_load_lds((const __attribute__((address_space(1))) void*)(g), (__attribute__((address_space(3))) void*)(l), 16, 0, 0)

#if __has_builtin(__builtin_amdgcn_exp2f)
#define EXP2(x) __builtin_amdgcn_exp2f(x)
#else
#define EXP2(x) exp2f(x)
#endif

__device__ inline uint32_t cvtpk_bf16(float lo, float hi) {
  uint32_t r;
  asm("v_cvt_pk_bf16_f32 %0, %1, %2" : "=v"(r) : "v"(lo), "v"(hi));
  return r;
}
__device__ inline void perm32swap(uint32_t& a, uint32_t& b) {
  asm volatile("v_permlane32_swap_b32 %0, %1" : "+v"(a), "+v"(b));
}

// ---------------- fused cast f32 -> bf16, all tensors ----------------
__global__ void cast_all(const float* __restrict__ embed, const float* __restrict__ Wq,
                         const float* __restrict__ Wk, const float* __restrict__ Wv,
                         const float* __restrict__ w1w, const float* __restrict__ w2w,
                         uint16_t* __restrict__ xbf, uint16_t* __restrict__ wqkv,
                         uint16_t* __restrict__ w1b, uint16_t* __restrict__ w2b) {
  const int i = (blockIdx.x * 256 + threadIdx.x) * 4;
  const float* src; uint16_t* dst; float sc = 1.f; int off;
  if (i < 4194304)       { src = embed; dst = xbf;            off = i; }
  else if (i < 5242880)  { src = Wq;  dst = wqkv;             off = i - 4194304; sc = 0.125f * 1.44269504f; }
  else if (i < 6291456)  { src = Wk;  dst = wqkv + 1048576;   off = i - 5242880; }
  else if (i < 7340032)  { src = Wv;  dst = wqkv + 2097152;   off = i - 6291456; }
  else if (i < 11534336) { src = w1w; dst = w1b;              off = i - 7340032; }
  else                   { src = w2w; dst = w2b;              off = i - 11534336; }
  float4 v = *(const float4*)(src + off);
  ushort4 o;
  o.x = f2bf(v.x * sc); o.y = f2bf(v.y * sc);
  o.z = f2bf(v.z * sc); o.w = f2bf(v.w * sc);
  *(ushort4*)(dst + off) = o;
}

// ---------------- 256x256 8-phase GEMM: C[M,N] = A[M,K]*B[N,K]^T ----------------
// 512 threads = 8 waves (2Mx4N). BK=64, LDS 128KB double-buffered.
// LDS swizzle: byte ^= (row&7)<<4, applied on pre-swizzled global source and on ds_read.
// blockIdx.z = split-K slice (K = per-slice extent, ldk = full row stride).
// EPI 0: bf16 out. EPI 1: bias+silu bf16 out. EPI 2: f32 out (+bias if kz==0).
template <int EPI>
__global__ __launch_bounds__(512, 2) void gemm256(
    const uint16_t* __restrict__ A, const uint16_t* __restrict__ Bm,
    void* __restrict__ C0, void* __restrict__ C1, void* __restrict__ C2, void* __restrict__ C3,
    const float* __restrict__ bias, int N, int K, int ldk) {
  __shared__ uint16_t Als[2][256 * 64];
  __shared__ uint16_t Bls[2][256 * 64];
  const int tid = threadIdx.x;
  const int l = tid & 63, w = tid >> 6;
  const int wm = w >> 2, wn = w & 3;

  // XCD-aware bijective swizzle (nwg % 8 == 0 for all our grids)
  const int gx = gridDim.x;
  const int nwg = gx * gridDim.y;
  const int orig = blockIdx.y * gx + blockIdx.x;
  const int wg = (orig & 7) * (nwg >> 3) + (orig >> 3);
  const int row0 = (wg % gx) * 256;
  const int col0 = (wg / gx) * 256;

  const int kz = blockIdx.z;
  const uint16_t* Ap = A + (size_t)kz * K;
  const uint16_t* Bp = Bm + (size_t)kz * K;
  void* Co = kz == 0 ? C0 : (kz == 1 ? C1 : (kz == 2 ? C2 : C3));

  // staging lane constants (pre-swizzled global source)
  const int srow = w * 8 + (l >> 3);                 // + q*64
  const int sgcol = ((l & 7) ^ (l >> 3)) * 8;        // element offset in K

  // ds_read lane constants (swizzled col bytes for kk=0,1)
  const int lr = l & 15;
  const int cb0 = ((l >> 4) * 16) ^ ((l & 7) << 4);
  const int cb1 = (64 + (l >> 4) * 16) ^ ((l & 7) << 4);

  auto issueA = [&](int buf, int t, int q) {
    const uint16_t* src = Ap + (size_t)(row0 + q * 64 + srow) * ldk + t * 64 + sgcol;
    GLOAD16(src, (char*)&Als[buf][0] + q * 8192 + w * 1024);
  };
  auto issueB = [&](int buf, int t, int q) {
    const uint16_t* src = Bp + (size_t)(col0 + q * 64 + srow) * ldk + t * 64 + sgcol;
    GLOAD16(src, (char*)&Bls[buf][0] + q * 8192 + w * 1024);
  };

  f32x4 acc[8][4] = {};
  bf16x8 a[4][2], b0[2][2], b1[2][2];

  auto lda = [&](int buf, int mh) {
#pragma unroll
    for (int m = 0; m < 4; ++m)
#pragma unroll
      for (int kk = 0; kk < 2; ++kk)
        a[m][kk] = *(const bf16x8*)((const char*)&Als[buf][0] +
                     (wm * 128 + (mh * 4 + m) * 16 + lr) * 128 + (kk ? cb1 : cb0));
  };
  auto ldb = [&](int buf, int nh, bf16x8 (&b)[2][2]) {
#pragma unroll
    for (int n = 0; n < 2; ++n)
#pragma unroll
      for (int kk = 0; kk < 2; ++kk)
        b[n][kk] = *(const bf16x8*)((const char*)&Bls[buf][0] +
                     (wn * 64 + (nh * 2 + n) * 16 + lr) * 128 + (kk ? cb1 : cb0));
  };

#define MMQUAD(MO, NO, B)                                              \
  {                                                                    \
    __builtin_amdgcn_s_setprio(1);                                     \
    _Pragma("unroll") for (int m = 0; m < 4; ++m)                      \
        _Pragma("unroll") for (int n = 0; n < 2; ++n)                  \
            _Pragma("unroll") for (int kk = 0; kk < 2; ++kk)           \
                acc[MO + m][NO + n] = MFMA16(a[m][kk], B[n][kk], acc[MO + m][NO + n]); \
    __builtin_amdgcn_s_setprio(0);                                     \
  }

  const int nt = K >> 6;
  // prologue: tile 0 fully issued into buf 0
#pragma unroll
  for (int q = 0; q < 4; ++q) { issueA(0, 0, q); issueB(0, 0, q); }

#pragma unroll 1
  for (int t = 0; t < nt; ++t) {
    const int buf = t & 1;
    __builtin_amdgcn_s_barrier();          // prev group done reading buf^1
    if (t + 1 < nt) {
#pragma unroll
      for (int q = 0; q < 4; ++q) issueA(buf ^ 1, t + 1, q);
      asm volatile("s_waitcnt vmcnt(4)" ::: "memory");   // tile t fully landed
    } else {
      asm volatile("s_waitcnt vmcnt(0)" ::: "memory");
    }
    __builtin_amdgcn_s_barrier();
    __builtin_amdgcn_sched_barrier(0);

    // phase 1: A(m0-3) + B(n0-1); prefetch B q0,q1
    lda(buf, 0); ldb(buf, 0, b0);
    if (t + 1 < nt) { issueB(buf ^ 1, t + 1, 0); issueB(buf ^ 1, t + 1, 1); }
    __builtin_amdgcn_s_barrier();
    MMQUAD(0, 0, b0)
    __builtin_amdgcn_s_barrier();

    // phase 2: B(n2-3); prefetch B q2,q3
    ldb(buf, 1, b1);
    if (t + 1 < nt) { issueB(buf ^ 1, t + 1, 2); issueB(buf ^ 1, t + 1, 3); }
    __builtin_amdgcn_s_barrier();
    MMQUAD(0, 2, b1)
    __builtin_amdgcn_s_barrier();

    // phase 3: A(m4-7)
    lda(buf, 1);
    __builtin_amdgcn_s_barrier();
    MMQUAD(4, 2, b1)
    __builtin_amdgcn_s_barrier();

    // phase 4 (boundary barrier follows)
    MMQUAD(4, 0, b0)
  }

  // ---- epilogue ----
  float bias_r[4];
  if (EPI != 0 && (EPI == 1 || kz == 0)) {
#pragma unroll
    for (int n = 0; n < 4; ++n) bias_r[n] = bias[col0 + wn * 64 + n * 16 + lr];
  }
#pragma unroll
  for (int m = 0; m < 8; ++m)
#pragma unroll
    for (int n = 0; n < 4; ++n)
#pragma unroll
      for (int v = 0; v < 4; ++v) {
        const int r = row0 + wm * 128 + m * 16 + ((l >> 4) << 2) + v;
        const int c = col0 + wn * 64 + n * 16 + lr;
        float x = acc[m][n][v];
        if (EPI == 0) {
          ((uint16_t*)Co)[(size_t)r * N + c] = f2bf(x);
        } else if (EPI == 1) {
          x += bias_r[n];
          float s = x / (1.f + __expf(-x));
          ((uint16_t*)Co)[(size_t)r * N + c] = f2bf(s);
        } else {
          if (kz == 0) x += bias_r[n];
          ((float*)Co)[(size_t)r * N + c] = x;
        }
      }
}

// ---------------- V transpose: qkv V slice -> Vt[bh][64 d][2048 s] ----------------
__global__ __launch_bounds__(256) void transpose_v(const uint16_t* __restrict__ qkv,
                                                   uint16_t* __restrict__ Vt) {
  __shared__ uint16_t t[64][72];
  const int kv0 = blockIdx.x * 64;
  const int bh = blockIdx.y;
  const size_t rowbase = (size_t)(bh >> 4) * 2048;
  const int hv = 2048 + (bh & 15) * 64;
  const int tid = threadIdx.x;
  const int r = tid >> 3, c8 = (tid & 7) * 8;
#pragma unroll
  for (int i = 0; i < 2; ++i) {
    const int row = i * 32 + r;
    u16x8 v = *(const u16x8*)(qkv + (rowbase + kv0 + row) * 3072 + hv + c8);
#pragma unroll
    for (int j = 0; j < 8; ++j) t[c8 + j][row] = v[j];
  }
  __syncthreads();
#pragma unroll
  for (int i = 0; i < 2; ++i) {
    const int d = i * 32 + r;
    u16x8 o;
#pragma unroll
    for (int j = 0; j < 8; ++j) o[j] = t[d][c8 + j];
    *(u16x8*)(Vt + ((size_t)bh * 64 + d) * 2048 + kv0 + c8) = o;
  }
}

// ---------------- flash attention (swapped QK^T, 32x32 MFMA) ----------------
__global__ __launch_bounds__(256, 2) void attn_kernel(const uint16_t* __restrict__ qkv,
                                                      const uint16_t* __restrict__ Vt,
                                                      float* __restrict__ out) {
  __shared__ uint16_t Klds[2][4096];
  __shared__ uint16_t Vlds[2][4096];
  const int tid = threadIdx.x;
  const int l = tid & 63, w = tid >> 6;
  const int lq = l & 31, hi = l >> 5;
  const int qt = blockIdx.x, bh = blockIdx.y;
  const size_t rowbase = (size_t)(bh >> 4) * 2048;
  const int h = bh & 15;
  const int hq = h * 64, hk = 1024 + h * 64;

  const int qrow = qt * 128 + w * 32 + lq;
  bf16x8 qf[4];
  {
    const uint16_t* qp = qkv + (rowbase + qrow) * 3072 + hq + hi * 8;
#pragma unroll
    for (int c = 0; c < 4; ++c) qf[c] = *(const bf16x8*)(qp + c * 16);
  }

  const int srow = w * 8 + (l >> 3);
  const int gcol = 8 * ((l & 7) ^ (l >> 3));

  f32x16 ot[2];
#pragma unroll
  for (int r = 0; r < 16; ++r) { ot[0][r] = 0.f; ot[1][r] = 0.f; }
  float m_run = -1e30f, l_run = 0.f;

  auto STAGE = [&](int buf, int kv0) {
#pragma unroll
    for (int p = 0; p < 2; ++p) {
      const uint16_t* srcK = qkv + (rowbase + kv0 + p * 32 + srow) * 3072 + hk + gcol;
      GLOAD16(srcK, (char*)&Klds[buf][0] + p * 4096 + w * 1024);
      const uint16_t* srcV = Vt + ((size_t)bh * 64 + p * 32 + srow) * 2048 + kv0 + gcol;
      GLOAD16(srcV, (char*)&Vlds[buf][0] + p * 4096 + w * 1024);
    }
  };

  STAGE(0, 0);
  int cur = 0;
  const int swz = (lq & 7) << 4;

  for (int t = 0; t < 32; ++t) {
    asm volatile("s_waitcnt vmcnt(0)" ::: "memory");
    __builtin_amdgcn_s_barrier();
    if (t < 31) STAGE(cur ^ 1, (t + 1) * 64);

    f32x16 st[2];
#pragma unroll
    for (int b = 0; b < 2; ++b) {
      f32x16 acm;
#pragma unroll
      for (int r = 0; r < 16; ++r) acm[r] = 0.f;
      __builtin_amdgcn_s_setprio(1);
#pragma unroll
      for (int c = 0; c < 4; ++c) {
        const int cb = (c * 32 + hi * 16) ^ swz;
        bf16x8 kf = *(const bf16x8*)((const char*)&Klds[cur][0] + (b * 32 + lq) * 128 + cb);
        acm = MFMA32(kf, qf[c], acm);
      }
      __builtin_amdgcn_s_setprio(0);
      st[b] = acm;
    }

    float mloc = st[0][0];
#pragma unroll
    for (int r = 1; r < 16; ++r) mloc = fmaxf(mloc, st[0][r]);
#pragma unroll
    for (int r = 0; r < 16; ++r) mloc = fmaxf(mloc, st[1][r]);
    const float mtile = fmaxf(mloc, __shfl_xor(mloc, 32, 64));
    if (!__all(mtile <= m_run + 8.f)) {
      const float mnew = fmaxf(m_run, mtile);
      const float sc = EXP2(m_run - mnew);
      m_run = mnew;
      l_run *= sc;
#pragma unroll
      for (int r = 0; r < 16; ++r) { ot[0][r] *= sc; ot[1][r] *= sc; }
    }
    float p0[16], p1[16];
    float rsum = 0.f;
#pragma unroll
    for (int r = 0; r < 16; ++r) { p0[r] = EXP2(st[0][r] - m_run); rsum += p0[r]; }
#pragma unroll
    for (int r = 0; r < 16; ++r) { p1[r] = EXP2(st[1][r] - m_run); rsum += p1[r]; }
    l_run += rsum + __shfl_xor(rsum, 32, 64);

    uint32_t pa[4][4];
#pragma unroll
    for (int b = 0; b < 2; ++b) {
      const float* pp = b ? p1 : p0;
#pragma unroll
      for (int c = 0; c < 2; ++c) {
        uint32_t a0 = cvtpk_bf16(pp[8 * c + 0], pp[8 * c + 1]);
        uint32_t a1 = cvtpk_bf16(pp[8 * c + 2], pp[8 * c + 3]);
        uint32_t b0 = cvtpk_bf16(pp[8 * c + 4], pp[8 * c + 5]);
        uint32_t b1 = cvtpk_bf16(pp[8 * c + 6], pp[8 * c + 7]);
        perm32swap(a0, b0);
        perm32swap(a1, b1);
        pa[b * 2 + c][0] = a0; pa[b * 2 + c][1] = a1;
        pa[b * 2 + c][2] = b0; pa[b * 2 + c][3] = b1;
      }
    }

    __builtin_amdgcn_s_setprio(1);
#pragma unroll
    for (int ks = 0; ks < 4; ++ks) {
      bf16x8 pf = *(bf16x8*)&pa[ks][0];
#pragma unroll
      for (int db = 0; db < 2; ++db) {
        const int cb = (ks * 32 + hi * 16) ^ swz;
        bf16x8 vf = *(const bf16x8*)((const char*)&Vlds[cur][0] + (db * 32 + lq) * 128 + cb);
        ot[db] = MFMA32(vf, pf, ot[db]);
      }
    }
    __builtin_amdgcn_s_setprio(0);
    cur ^= 1;
  }

  const float linv = 1.f / l_run;
  float* orow = out + (rowbase + qrow) * 1024 + h * 64;
#pragma unroll
  for (int db = 0; db < 2; ++db)
#pragma unroll
    for (int m = 0; m < 4; ++m) {
      float4 v;
      v.x = ot[db][4 * m + 0] * linv;
      v.y = ot[db][4 * m + 1] * linv;
      v.z = ot[db][4 * m + 2] * linv;
      v.w = ot[db][4 * m + 3] * linv;
      *(float4*)(orow + db * 32 + 8 * m + 4 * hi) = v;
    }
}

// ---------------- residual + layernorm: y = LN(x0+x1[+x2+x3+x4]) * g + b ----------------
__global__ __launch_bounds__(256) void ln_kernel(const float* __restrict__ x0p,
                                                 const float* __restrict__ x1p,
                                                 const float* __restrict__ x2p,
                                                 const float* __restrict__ x3p,
                                                 const float* __restrict__ x4p,
                                                 const float* __restrict__ g,
                                                 const float* __restrict__ b,
                                                 float* __restrict__ y32,
                                                 uint16_t* __restrict__ y16) {
  const int row = blockIdx.x;
  const int t = threadIdx.x;
  const int l = t & 63, w = t >> 6;
  float4 va = *((const float4*)(x0p + (size_t)row * 1024) + t);
  float4 vb = *((const float4*)(x1p + (size_t)row * 1024) + t);
  float x0 = va.x + vb.x, x1 = va.y + vb.y, x2 = va.z + vb.z, x3 = va.w + vb.w;
  if (x2p) {
    float4 vc = *((const float4*)(x2p + (size_t)row * 1024) + t);
    x0 += vc.x; x1 += vc.y; x2 += vc.z; x3 += vc.w;
  }
  if (x3p) {
    float4 vc = *((const float4*)(x3p + (size_t)row * 1024) + t);
    x0 += vc.x; x1 += vc.y; x2 += vc.z; x3 += vc.w;
  }
  if (x4p) {
    float4 vc = *((const float4*)(x4p + (size_t)row * 1024) + t);
    x0 += vc.x; x1 += vc.y; x2 += vc.z; x3 += vc.w;
  }
  float s = x0 + x1 + x2 + x3;
  float q = x0 * x0 + x1 * x1 + x2 * x2 + x3 * x3;
#pragma unroll
  for (int off = 1; off < 64; off <<= 1) {
    s += __shfl_xor(s, off, 64);
    q += __shfl_xor(q, off, 64);
  }
  __shared__ float red[8];
  if (l == 0) { red[w] = s; red[w + 4] = q; }
  __syncthreads();
  s = red[0] + red[1] + red[2] + red[3];
  q = red[4] + red[5] + red[6] + red[7];
  const float mu = s * (1.f / 1024.f);
  const float var = q * (1.f / 1024.f) - mu * mu;
  const float rstd = rsqrtf(var + 1e-5f);
  float4 vg = *((const float4*)g + t);
  float4 vbb = *((const float4*)b + t);
  float y0 = (x0 - mu) * rstd * vg.x + vbb.x;
  float y1 = (x1 - mu) * rstd * vg.y + vbb.y;
  float y2 = (x2 - mu) * rstd * vg.z + vbb.z;
  float y3 = (x3 - mu) * rstd * vg.w + vbb.w;
  *((float4*)(y32 + (size_t)row * 1024) + t) = make_float4(y0, y1, y2, y3);
  if (y16) {
    union { uint16_t u[4]; uint64_t v; } o;
    o.u[0] = f2bf(y0); o.u[1] = f2bf(y1); o.u[2] = f2bf(y2); o.u[3] = f2bf(y3);
    *((uint64_t*)(y16 + (size_t)row * 1024) + t) = o.v;
  }
}

extern "C" void kernel_launch(void* const* d_in, const int* in_sizes, int n_in,
                              void* d_out, int out_size, void* d_ws, size_t ws_size,
                              hipStream_t stream) {
  const float* embed = (const float*)d_in[0];
  const float* Wk = (const float*)d_in[1];
  const float* Wq = (const float*)d_in[2];
  const float* Wv = (const float*)d_in[3];
  const float* w1w = (const float*)d_in[4];
  const float* w1bias = (const float*)d_in[5];
  const float* w2w = (const float*)d_in[6];
  const float* w2bias = (const float*)d_in[7];
  const float* lng = (const float*)d_in[8];
  const float* lnb = (const float*)d_in[9];
  const float* ln2g = (const float*)d_in[10];
  const float* ln2b = (const float*)d_in[11];

  char* ws = (char*)d_ws;
  uint16_t* qkv  = (uint16_t*)(ws);                  // 25165824 ; later FFN2 partial1
  uint16_t* xbf  = (uint16_t*)(ws + 25165824);       // 8388608 ; with wqkv+w1b later partial2
  uint16_t* wqkv = (uint16_t*)(ws + 33554432);       // 6291456
  uint16_t* w1b  = (uint16_t*)(ws + 39845888);       // 8388608
  uint16_t* w2b  = (uint16_t*)(ws + 48234496);       // 8388608
  float*    attf = (float*)(ws + 56623104);          // 16777216
  float*    yf   = (float*)(ws + 73400320);          // 16777216
  uint16_t* hid  = (uint16_t*)(ws + 90177536);       // 33554432 (FFN1 out)
  uint16_t* Vt   = (uint16_t*)(ws + 90177536);       // 8388608 (only live pre-FFN1)
  float*    part1 = (float*)qkv;                     // FFN2 slice-1 partial
  float*    part2 = (float*)(ws + 25165824);         // FFN2 slice-2 partial (xbf/wqkv/w1b dead)
  float*    part3 = (float*)d_out;                   // FFN2 slice-3 partial (overwritten by LN2)

  cast_all<<<dim3(15360), dim3(256), 0, stream>>>(embed, Wq, Wk, Wv, w1w, w2w,
                                                  xbf, wqkv, w1b, w2b);

  // QKV projection: [4096,1024] x [3072,1024]^T -> [4096,3072] bf16
  gemm256<0><<<dim3(16, 12), dim3(512), 0, stream>>>(xbf, wqkv, qkv, nullptr, nullptr, nullptr,
                                                     nullptr, 3072, 1024, 1024);
  // V transpose
  transpose_v<<<dim3(32, 32), dim3(256), 0, stream>>>(qkv, Vt);
  // attention
  attn_kernel<<<dim3(16, 32), dim3(256), 0, stream>>>(qkv, Vt, attf);
  // residual + LN1 -> yf (f32), xbf (bf16)
  ln_kernel<<<dim3(4096), dim3(256), 0, stream>>>(attf, embed, nullptr, nullptr, nullptr,
                                                  lng, lnb, yf, xbf);
  // FFN1: silu(y @ w1^T + b1) -> hid bf16
  gemm256<1><<<dim3(16, 16), dim3(512), 0, stream>>>(xbf, w1b, hid, nullptr, nullptr, nullptr,
                                                     w1bias, 4096, 1024, 1024);
  // FFN2 split-K=4, one dispatch: slice0->attf(+bias), 1->part1, 2->part2, 3->part3
  gemm256<2><<<dim3(16, 4, 4), dim3(512), 0, stream>>>(hid, w2b, attf, part1, part2, part3,
                                                       w2bias, 1024, 1024, 4096);
  // residual + LN2: attf+part1+part2+part3+yf -> d_out
  ln_kernel<<<dim3(4096), dim3(256), 0, stream>>>(attf, part1, part2, part3, yf,
                                                  ln2g, ln2b, (float*)d_out, nullptr);
}